// Round 1
// baseline (1639.216 us; speedup 1.0000x reference)
//
#include <hip/hip_runtime.h>

#define N_NODESC 100000
#define N_EDGESC 1600000
#define N_GRAPHSC 64
#define HIDC 128
#define NCLSC 696

typedef __attribute__((ext_vector_type(8))) short short8;
typedef __attribute__((ext_vector_type(4))) float f32x4;

__device__ __forceinline__ ushort f2b(float x) {
  union { float f; unsigned u; } a; a.f = x;
  unsigned r = a.u + 0x7FFFu + ((a.u >> 16) & 1u);
  return (ushort)(r >> 16);
}
__device__ __forceinline__ float b2f(ushort b) {
  union { float f; unsigned u; } a; a.u = ((unsigned)b) << 16;
  return a.f;
}

// ---------------- CSR build ----------------
__global__ void k_hist(const int* __restrict__ ei, int* __restrict__ cnt, int E) {
  int e = blockIdx.x * 256 + threadIdx.x;
  if (e < E) atomicAdd(&cnt[ei[E + e] + 1], 1);
}

__global__ __launch_bounds__(1024) void k_scan1(const int* __restrict__ cnt,
                                                int* __restrict__ rowptr,
                                                int* __restrict__ bsums, int n) {
  __shared__ int wsum[16];
  int t = threadIdx.x, b = blockIdx.x;
  int i = b * 1024 + t;
  int v = (i < n) ? cnt[i] : 0;
  int lane = t & 63, w = t >> 6;
  for (int d = 1; d < 64; d <<= 1) {
    int u = __shfl_up(v, (unsigned)d, 64);
    if (lane >= d) v += u;
  }
  if (lane == 63) wsum[w] = v;
  __syncthreads();
  if (w == 0) {
    int s = (lane < 16) ? wsum[lane] : 0;
    for (int d = 1; d < 16; d <<= 1) {
      int u = __shfl_up(s, (unsigned)d, 64);
      if (lane >= d) s += u;
    }
    if (lane < 16) wsum[lane] = s;
  }
  __syncthreads();
  int add = (w > 0) ? wsum[w - 1] : 0;
  v += add;
  if (i < n) rowptr[i] = v;
  if (t == 1023) bsums[b] = v;
}

__global__ void k_scan2(int* bsums, int nb) {
  if (threadIdx.x == 0) {
    int s = 0;
    for (int i = 0; i < nb; ++i) { s += bsums[i]; bsums[i] = s; }
  }
}

__global__ __launch_bounds__(1024) void k_scan3(int* __restrict__ rowptr,
                                                const int* __restrict__ bsums,
                                                int* __restrict__ cursor, int n) {
  int b = blockIdx.x;
  int i = b * 1024 + threadIdx.x;
  if (i >= n) return;
  int off = (b > 0) ? bsums[b - 1] : 0;
  int v = rowptr[i] + off;
  rowptr[i] = v;
  cursor[i] = v;
}

__global__ void k_scatter(const int* __restrict__ ei, int* __restrict__ cursor,
                          int* __restrict__ col, int E) {
  int e = blockIdx.x * 256 + threadIdx.x;
  if (e < E) {
    int d = ei[E + e];
    int pos = atomicAdd(&cursor[d], 1);
    col[pos] = ei[e];  // src
  }
}

// ---------------- weight split (transpose + hi/lo bf16) ----------------
// out layout: 8 matrices [128][128], WT[n][k] = W[k][n]; mats 0-3 = W1 layers, 4-7 = W2 layers
__global__ void k_wsplit(const float* __restrict__ W1s, const float* __restrict__ W2s,
                         ushort* __restrict__ hi, ushort* __restrict__ lo) {
  int idx = blockIdx.x * 256 + threadIdx.x;  // 8*16384
  if (idx >= 8 * 16384) return;
  int m = idx >> 14;
  int r = (idx >> 7) & 127;  // n (output col)
  int k = idx & 127;
  const float* W = (m < 4) ? (W1s + (size_t)m * 16384) : (W2s + (size_t)(m - 4) * 16384);
  float v = W[k * 128 + r];
  ushort vh = f2b(v);
  float res = v - b2f(vh);
  hi[idx] = vh;
  lo[idx] = f2b(res);
}

// ---------------- aggregation: z[n] = h[n] + sum_{j} h[col[j]] ----------------
__global__ __launch_bounds__(256) void k_aggr(const float* __restrict__ hin,
                                              const int* __restrict__ rowptr,
                                              const int* __restrict__ col,
                                              float* __restrict__ z, int n_nodes) {
  int node = blockIdx.x * 4 + (threadIdx.x >> 6);
  if (node >= n_nodes) return;
  int lane = threadIdx.x & 63;
  const float2* base = (const float2*)hin;
  float2 self = base[(size_t)node * 64 + lane];
  float accx = self.x, accy = self.y;
  int j = rowptr[node], e = rowptr[node + 1];
  for (; j + 2 <= e; j += 2) {
    int s0 = col[j], s1 = col[j + 1];
    float2 v0 = base[(size_t)s0 * 64 + lane];
    float2 v1 = base[(size_t)s1 * 64 + lane];
    accx += v0.x + v1.x;
    accy += v0.y + v1.y;
  }
  if (j < e) {
    int s0 = col[j];
    float2 v0 = base[(size_t)s0 * 64 + lane];
    accx += v0.x;
    accy += v0.y;
  }
  float2 o; o.x = accx; o.y = accy;
  ((float2*)z)[(size_t)node * 64 + lane] = o;
}

// ---------------- GEMM: C = relu(A @ W + bias), A [M][128] f32, W via WT hi/lo bf16 ----------------
__global__ __launch_bounds__(256) void k_gemm(const float* A,
                                              const ushort* __restrict__ WThi,
                                              const ushort* __restrict__ WTlo,
                                              const float* __restrict__ bias,
                                              float* C, int M) {
  __shared__ __align__(16) char smem[34816];
  ushort* ahi = (ushort*)smem;            // [64][136]
  ushort* alo = ahi + 64 * 136;           // [64][136]
  float* ldsC = (float*)smem;             // [64][132] (reused after barrier)

  int t = threadIdx.x;
  int row0 = blockIdx.x * 64;

  // stage A tile: 64 rows x 128 f32 -> hi/lo bf16, padded stride 136
  for (int c = t; c < 2048; c += 256) {
    int r = c >> 5;
    int c4 = (c & 31) << 2;
    int gr = row0 + r;
    if (gr >= M) gr = M - 1;
    f32x4 v = *(const f32x4*)&A[(size_t)gr * 128 + c4];
    ushort h4[4], l4[4];
#pragma unroll
    for (int q = 0; q < 4; ++q) {
      ushort vh = f2b(v[q]);
      h4[q] = vh;
      l4[q] = f2b(v[q] - b2f(vh));
    }
    ushort* ph = &ahi[r * 136 + c4];
    ushort* pl = &alo[r * 136 + c4];
    ph[0] = h4[0]; ph[1] = h4[1]; ph[2] = h4[2]; ph[3] = h4[3];
    pl[0] = l4[0]; pl[1] = l4[1]; pl[2] = l4[2]; pl[3] = l4[3];
  }
  __syncthreads();

  int lane = t & 63, w = t >> 6;
  int lrow = w * 16 + (lane & 15);
  int koff = (lane >> 4) * 8;
  int lbase = lrow * 136;

  f32x4 acc[8];
#pragma unroll
  for (int n = 0; n < 8; ++n) acc[n] = (f32x4){0.f, 0.f, 0.f, 0.f};

#pragma unroll
  for (int ks = 0; ks < 4; ++ks) {
    short8 a_h = *(const short8*)&ahi[lbase + ks * 32 + koff];
    short8 a_l = *(const short8*)&alo[lbase + ks * 32 + koff];
#pragma unroll
    for (int n = 0; n < 8; ++n) {
      int widx = (n * 16 + (lane & 15)) * 128 + ks * 32 + koff;
      short8 b_h = *(const short8*)&WThi[widx];
      short8 b_l = *(const short8*)&WTlo[widx];
      acc[n] = __builtin_amdgcn_mfma_f32_16x16x32_bf16(a_h, b_h, acc[n], 0, 0, 0);
      acc[n] = __builtin_amdgcn_mfma_f32_16x16x32_bf16(a_h, b_l, acc[n], 0, 0, 0);
      acc[n] = __builtin_amdgcn_mfma_f32_16x16x32_bf16(a_l, b_h, acc[n], 0, 0, 0);
    }
  }
  __syncthreads();  // all A reads done; smem reused as ldsC

  // epilogue: bias + relu -> ldsC (stride 132)
  int colb = lane & 15;
  int rbase = (lane >> 4) * 4;
#pragma unroll
  for (int n = 0; n < 8; ++n) {
    float bv = bias[n * 16 + colb];
#pragma unroll
    for (int r = 0; r < 4; ++r) {
      float v = acc[n][r] + bv;
      v = fmaxf(v, 0.f);
      ldsC[(w * 16 + rbase + r) * 132 + n * 16 + colb] = v;
    }
  }
  __syncthreads();

  // coalesced f32x4 stores
  for (int c = t; c < 2048; c += 256) {
    int r = c >> 5;
    int c4 = (c & 31) << 2;
    int gr = row0 + r;
    if (gr < M) {
      f32x4 v;
      v[0] = ldsC[r * 132 + c4 + 0];
      v[1] = ldsC[r * 132 + c4 + 1];
      v[2] = ldsC[r * 132 + c4 + 2];
      v[3] = ldsC[r * 132 + c4 + 3];
      *(f32x4*)&C[(size_t)gr * 128 + c4] = v;
    }
  }
}

// ---------------- global add pool (batch sorted) ----------------
__global__ __launch_bounds__(128) void k_pool(const float* __restrict__ h,
                                              const int* __restrict__ batch,
                                              float* __restrict__ g, int n_nodes) {
  __shared__ int slo, shi;
  int gr = blockIdx.x;
  int f = threadIdx.x;
  if (f == 0) {
    int lo = 0, hi = n_nodes;
    while (lo < hi) { int m = (lo + hi) >> 1; if (batch[m] < gr) lo = m + 1; else hi = m; }
    slo = lo;
    lo = 0; hi = n_nodes;
    while (lo < hi) { int m = (lo + hi) >> 1; if (batch[m] < gr + 1) lo = m + 1; else hi = m; }
    shi = lo;
  }
  __syncthreads();
  float acc = 0.f;
  for (int n = slo; n < shi; ++n) acc += h[(size_t)n * 128 + f];
  g[gr * 128 + f] = acc;
}

// ---------------- head: fc1+relu, fc2, log_softmax ----------------
__global__ __launch_bounds__(128) void k_head(const float* __restrict__ g,
                                              const float* __restrict__ fc1w,
                                              const float* __restrict__ fc1b,
                                              const float* __restrict__ fc2w,
                                              const float* __restrict__ fc2b,
                                              float* __restrict__ out) {
  __shared__ float gs[128], a1[128], lg[696];
  __shared__ float wred[2];
  int gr = blockIdx.x, t = threadIdx.x;
  gs[t] = g[gr * 128 + t];
  __syncthreads();
  float acc = fc1b[t];
  for (int k = 0; k < 128; ++k) acc += gs[k] * fc1w[k * 128 + t];
  a1[t] = fmaxf(acc, 0.f);
  __syncthreads();
  for (int c = t; c < 696; c += 128) {
    float s = fc2b[c];
    for (int k = 0; k < 128; ++k) s += a1[k] * fc2w[k * 696 + c];
    lg[c] = s;
  }
  __syncthreads();
  float m = -__builtin_inff();
  for (int c = t; c < 696; c += 128) m = fmaxf(m, lg[c]);
  for (int d = 32; d; d >>= 1) m = fmaxf(m, __shfl_xor(m, d, 64));
  if ((t & 63) == 0) wred[t >> 6] = m;
  __syncthreads();
  m = fmaxf(wred[0], wred[1]);
  __syncthreads();
  float se = 0.f;
  for (int c = t; c < 696; c += 128) se += expf(lg[c] - m);
  for (int d = 32; d; d >>= 1) se += __shfl_xor(se, d, 64);
  __shared__ float wred2[2];
  if ((t & 63) == 0) wred2[t >> 6] = se;
  __syncthreads();
  float lse = m + logf(wred2[0] + wred2[1]);
  for (int c = t; c < 696; c += 128) out[gr * 696 + c] = lg[c] - lse;
}

extern "C" void kernel_launch(void* const* d_in, const int* in_sizes, int n_in,
                              void* d_out, int out_size, void* d_ws, size_t ws_size,
                              hipStream_t stream) {
  const float* x    = (const float*)d_in[0];
  const int*   ei   = (const int*)d_in[1];
  const int*   batch= (const int*)d_in[2];
  const float* W1s  = (const float*)d_in[3];
  const float* b1s  = (const float*)d_in[4];
  const float* W2s  = (const float*)d_in[5];
  const float* b2s  = (const float*)d_in[6];
  const float* fc1w = (const float*)d_in[7];
  const float* fc1b = (const float*)d_in[8];
  const float* fc2w = (const float*)d_in[9];
  const float* fc2b = (const float*)d_in[10];
  float* out = (float*)d_out;

  char* ws = (char*)d_ws;
  size_t off = 0;
  auto alloc = [&](size_t bytes) -> void* {
    void* p = ws + off;
    off = (off + bytes + 255) & ~(size_t)255;
    return p;
  };
  float* z      = (float*)alloc((size_t)N_NODESC * 128 * 4);
  float* h      = (float*)alloc((size_t)N_NODESC * 128 * 4);
  int*   col    = (int*)alloc((size_t)N_EDGESC * 4);
  int*   rowptr = (int*)alloc((size_t)(N_NODESC + 1) * 4);
  int*   cursor = (int*)alloc((size_t)(N_NODESC + 1) * 4);
  int*   bsums  = (int*)alloc(128 * 4);
  float* g      = (float*)alloc(64 * 128 * 4);
  ushort* wthi  = (ushort*)alloc((size_t)8 * 16384 * 2);
  ushort* wtlo  = (ushort*)alloc((size_t)8 * 16384 * 2);

  const int n_scan = N_NODESC + 1;
  const int NB = (n_scan + 1023) / 1024;  // 98

  // CSR build (cursor doubles as counts)
  hipMemsetAsync(cursor, 0, (size_t)(N_NODESC + 1) * 4, stream);
  k_hist<<<dim3((N_EDGESC + 255) / 256), dim3(256), 0, stream>>>(ei, cursor, N_EDGESC);
  k_scan1<<<dim3(NB), dim3(1024), 0, stream>>>(cursor, rowptr, bsums, n_scan);
  k_scan2<<<dim3(1), dim3(64), 0, stream>>>(bsums, NB);
  k_scan3<<<dim3(NB), dim3(1024), 0, stream>>>(rowptr, bsums, cursor, n_scan);
  k_scatter<<<dim3((N_EDGESC + 255) / 256), dim3(256), 0, stream>>>(ei, cursor, col, N_EDGESC);

  // weight preprocessing
  k_wsplit<<<dim3(512), dim3(256), 0, stream>>>(W1s, W2s, wthi, wtlo);

  // 4 GIN layers
  for (int L = 0; L < 4; ++L) {
    const float* hin = (L == 0) ? x : h;
    k_aggr<<<dim3(N_NODESC / 4), dim3(256), 0, stream>>>(hin, rowptr, col, z, N_NODESC);
    k_gemm<<<dim3((N_NODESC + 63) / 64), dim3(256), 0, stream>>>(
        z, wthi + (size_t)L * 16384, wtlo + (size_t)L * 16384, b1s + L * 128, z, N_NODESC);
    k_gemm<<<dim3((N_NODESC + 63) / 64), dim3(256), 0, stream>>>(
        z, wthi + (size_t)(4 + L) * 16384, wtlo + (size_t)(4 + L) * 16384, b2s + L * 128, h, N_NODESC);
  }

  // pool + head
  k_pool<<<dim3(64), dim3(128), 0, stream>>>(h, batch, g, N_NODESC);
  k_head<<<dim3(64), dim3(128), 0, stream>>>(g, fc1w, fc1b, fc2w, fc2b, out);
}

// Round 2
// 1283.342 us; speedup vs baseline: 1.2773x; 1.2773x over previous
//
#include <hip/hip_runtime.h>

#define N_NODESC 100000
#define N_EDGESC 1600000
#define N_GRAPHSC 64
#define HIDC 128
#define NCLSC 696

typedef __attribute__((ext_vector_type(8))) short short8;
typedef __attribute__((ext_vector_type(4))) float f32x4;

__device__ __forceinline__ ushort f2b(float x) {
  union { float f; unsigned u; } a; a.f = x;
  unsigned r = a.u + 0x7FFFu + ((a.u >> 16) & 1u);
  return (ushort)(r >> 16);
}
__device__ __forceinline__ float b2f(ushort b) {
  union { float f; unsigned u; } a; a.u = ((unsigned)b) << 16;
  return a.f;
}

// ---------------- CSR build ----------------
__global__ void k_hist(const int* __restrict__ ei, int* __restrict__ cnt, int E) {
  int e = blockIdx.x * 256 + threadIdx.x;
  if (e < E) atomicAdd(&cnt[ei[E + e] + 1], 1);
}

__global__ __launch_bounds__(1024) void k_scan1(const int* __restrict__ cnt,
                                                int* __restrict__ rowptr,
                                                int* __restrict__ bsums, int n) {
  __shared__ int wsum[16];
  int t = threadIdx.x, b = blockIdx.x;
  int i = b * 1024 + t;
  int v = (i < n) ? cnt[i] : 0;
  int lane = t & 63, w = t >> 6;
  for (int d = 1; d < 64; d <<= 1) {
    int u = __shfl_up(v, (unsigned)d, 64);
    if (lane >= d) v += u;
  }
  if (lane == 63) wsum[w] = v;
  __syncthreads();
  if (w == 0) {
    int s = (lane < 16) ? wsum[lane] : 0;
    for (int d = 1; d < 16; d <<= 1) {
      int u = __shfl_up(s, (unsigned)d, 64);
      if (lane >= d) s += u;
    }
    if (lane < 16) wsum[lane] = s;
  }
  __syncthreads();
  int add = (w > 0) ? wsum[w - 1] : 0;
  v += add;
  if (i < n) rowptr[i] = v;
  if (t == 1023) bsums[b] = v;
}

__global__ void k_scan2(int* bsums, int nb) {
  if (threadIdx.x == 0) {
    int s = 0;
    for (int i = 0; i < nb; ++i) { s += bsums[i]; bsums[i] = s; }
  }
}

__global__ __launch_bounds__(1024) void k_scan3(int* __restrict__ rowptr,
                                                const int* __restrict__ bsums,
                                                int* __restrict__ cursor, int n) {
  int b = blockIdx.x;
  int i = b * 1024 + threadIdx.x;
  if (i >= n) return;
  int off = (b > 0) ? bsums[b - 1] : 0;
  int v = rowptr[i] + off;
  rowptr[i] = v;
  cursor[i] = v;
}

__global__ void k_scatter(const int* __restrict__ ei, int* __restrict__ cursor,
                          int* __restrict__ col, int E) {
  int e = blockIdx.x * 256 + threadIdx.x;
  if (e < E) {
    int d = ei[E + e];
    int pos = atomicAdd(&cursor[d], 1);
    col[pos] = ei[e];  // src
  }
}

// ---------------- weight split (transpose + hi/lo bf16) ----------------
__global__ void k_wsplit(const float* __restrict__ W1s, const float* __restrict__ W2s,
                         ushort* __restrict__ hi, ushort* __restrict__ lo) {
  int idx = blockIdx.x * 256 + threadIdx.x;  // 8*16384
  if (idx >= 8 * 16384) return;
  int m = idx >> 14;
  int r = (idx >> 7) & 127;  // n (output col)
  int k = idx & 127;
  const float* W = (m < 4) ? (W1s + (size_t)m * 16384) : (W2s + (size_t)(m - 4) * 16384);
  float v = W[k * 128 + r];
  ushort vh = f2b(v);
  float res = v - b2f(vh);
  hi[idx] = vh;
  lo[idx] = f2b(res);
}

// ---------------- aggregation: z[n] = h[n] + sum_{j} h[col[j]] ----------------
__global__ __launch_bounds__(256) void k_aggr(const float* __restrict__ hin,
                                              const int* __restrict__ rowptr,
                                              const int* __restrict__ col,
                                              float* __restrict__ z, int n_nodes) {
  int node = blockIdx.x * 4 + (threadIdx.x >> 6);
  if (node >= n_nodes) return;
  int lane = threadIdx.x & 63;
  const float2* base = (const float2*)hin;
  float2 self = base[(size_t)node * 64 + lane];
  float accx = self.x, accy = self.y;
  int j = rowptr[node], e = rowptr[node + 1];
  for (; j + 2 <= e; j += 2) {
    int s0 = col[j], s1 = col[j + 1];
    float2 v0 = base[(size_t)s0 * 64 + lane];
    float2 v1 = base[(size_t)s1 * 64 + lane];
    accx += v0.x + v1.x;
    accy += v0.y + v1.y;
  }
  if (j < e) {
    int s0 = col[j];
    float2 v0 = base[(size_t)s0 * 64 + lane];
    accx += v0.x;
    accy += v0.y;
  }
  float2 o; o.x = accx; o.y = accy;
  ((float2*)z)[(size_t)node * 64 + lane] = o;
}

// ---------------- GEMM: C = relu(A @ W + bias), A [M][128] f32, W via WT hi/lo bf16 ----------------
__global__ __launch_bounds__(256) void k_gemm(const float* A,
                                              const ushort* __restrict__ WThi,
                                              const ushort* __restrict__ WTlo,
                                              const float* __restrict__ bias,
                                              float* C, int M) {
  __shared__ __align__(16) char smem[34816];
  ushort* ahi = (ushort*)smem;            // [64][136]
  ushort* alo = ahi + 64 * 136;           // [64][136]
  float* ldsC = (float*)smem;             // [64][132] (reused after barrier)

  int t = threadIdx.x;
  int row0 = blockIdx.x * 64;

  // stage A tile: 64 rows x 128 f32 -> hi/lo bf16, padded stride 136
  for (int c = t; c < 2048; c += 256) {
    int r = c >> 5;
    int c4 = (c & 31) << 2;
    int gr = row0 + r;
    if (gr >= M) gr = M - 1;
    f32x4 v = *(const f32x4*)&A[(size_t)gr * 128 + c4];
    ushort h4[4], l4[4];
#pragma unroll
    for (int q = 0; q < 4; ++q) {
      ushort vh = f2b(v[q]);
      h4[q] = vh;
      l4[q] = f2b(v[q] - b2f(vh));
    }
    ushort* ph = &ahi[r * 136 + c4];
    ushort* pl = &alo[r * 136 + c4];
    ph[0] = h4[0]; ph[1] = h4[1]; ph[2] = h4[2]; ph[3] = h4[3];
    pl[0] = l4[0]; pl[1] = l4[1]; pl[2] = l4[2]; pl[3] = l4[3];
  }
  __syncthreads();

  int lane = t & 63, w = t >> 6;
  int lrow = w * 16 + (lane & 15);
  int koff = (lane >> 4) * 8;
  int lbase = lrow * 136;

  f32x4 acc[8];
#pragma unroll
  for (int n = 0; n < 8; ++n) acc[n] = (f32x4){0.f, 0.f, 0.f, 0.f};

#pragma unroll
  for (int ks = 0; ks < 4; ++ks) {
    short8 a_h = *(const short8*)&ahi[lbase + ks * 32 + koff];
    short8 a_l = *(const short8*)&alo[lbase + ks * 32 + koff];
#pragma unroll
    for (int n = 0; n < 8; ++n) {
      int widx = (n * 16 + (lane & 15)) * 128 + ks * 32 + koff;
      short8 b_h = *(const short8*)&WThi[widx];
      short8 b_l = *(const short8*)&WTlo[widx];
      acc[n] = __builtin_amdgcn_mfma_f32_16x16x32_bf16(a_h, b_h, acc[n], 0, 0, 0);
      acc[n] = __builtin_amdgcn_mfma_f32_16x16x32_bf16(a_h, b_l, acc[n], 0, 0, 0);
      acc[n] = __builtin_amdgcn_mfma_f32_16x16x32_bf16(a_l, b_h, acc[n], 0, 0, 0);
    }
  }
  __syncthreads();  // all A reads done; smem reused as ldsC

  // epilogue: bias + relu -> ldsC (stride 132)
  int colb = lane & 15;
  int rbase = (lane >> 4) * 4;
#pragma unroll
  for (int n = 0; n < 8; ++n) {
    float bv = bias[n * 16 + colb];
#pragma unroll
    for (int r = 0; r < 4; ++r) {
      float v = acc[n][r] + bv;
      v = fmaxf(v, 0.f);
      ldsC[(w * 16 + rbase + r) * 132 + n * 16 + colb] = v;
    }
  }
  __syncthreads();

  // coalesced f32x4 stores
  for (int c = t; c < 2048; c += 256) {
    int r = c >> 5;
    int c4 = (c & 31) << 2;
    int gr = row0 + r;
    if (gr < M) {
      f32x4 v;
      v[0] = ldsC[r * 132 + c4 + 0];
      v[1] = ldsC[r * 132 + c4 + 1];
      v[2] = ldsC[r * 132 + c4 + 2];
      v[3] = ldsC[r * 132 + c4 + 3];
      *(f32x4*)&C[(size_t)gr * 128 + c4] = v;
    }
  }
}

// ---------------- global add pool: wave-per-64-node-chunk, atomic flush ----------------
// batch is sorted, so most 64-node chunks lie in one graph (fast path).
__global__ __launch_bounds__(256) void k_pool(const float* __restrict__ h,
                                              const int* __restrict__ batch,
                                              float* __restrict__ g, int n_nodes) {
  int wave = (blockIdx.x * 256 + threadIdx.x) >> 6;  // global wave id
  int lane = threadIdx.x & 63;
  int n0 = wave * 64;
  if (n0 >= n_nodes) return;
  int n1 = n0 + 64;
  if (n1 > n_nodes) n1 = n_nodes;
  const float2* base = (const float2*)h;
  float accx = 0.f, accy = 0.f;
  int curg = batch[n0];
  int lastg = batch[n1 - 1];
  if (curg == lastg) {
    int n = n0;
    for (; n + 4 <= n1; n += 4) {
      float2 v0 = base[(size_t)n * 64 + lane];
      float2 v1 = base[(size_t)(n + 1) * 64 + lane];
      float2 v2 = base[(size_t)(n + 2) * 64 + lane];
      float2 v3 = base[(size_t)(n + 3) * 64 + lane];
      accx += (v0.x + v1.x) + (v2.x + v3.x);
      accy += (v0.y + v1.y) + (v2.y + v3.y);
    }
    for (; n < n1; ++n) {
      float2 v = base[(size_t)n * 64 + lane];
      accx += v.x; accy += v.y;
    }
    atomicAdd(&g[curg * 128 + 2 * lane], accx);
    atomicAdd(&g[curg * 128 + 2 * lane + 1], accy);
  } else {
    for (int n = n0; n < n1; ++n) {
      int b = batch[n];
      if (b != curg) {
        atomicAdd(&g[curg * 128 + 2 * lane], accx);
        atomicAdd(&g[curg * 128 + 2 * lane + 1], accy);
        accx = 0.f; accy = 0.f; curg = b;
      }
      float2 v = base[(size_t)n * 64 + lane];
      accx += v.x; accy += v.y;
    }
    atomicAdd(&g[curg * 128 + 2 * lane], accx);
    atomicAdd(&g[curg * 128 + 2 * lane + 1], accy);
  }
}

// ---------------- head: fc1+relu, fc2, log_softmax ----------------
__global__ __launch_bounds__(128) void k_head(const float* __restrict__ g,
                                              const float* __restrict__ fc1w,
                                              const float* __restrict__ fc1b,
                                              const float* __restrict__ fc2w,
                                              const float* __restrict__ fc2b,
                                              float* __restrict__ out) {
  __shared__ float gs[128], a1[128], lg[696];
  __shared__ float wred[2];
  int gr = blockIdx.x, t = threadIdx.x;
  gs[t] = g[gr * 128 + t];
  __syncthreads();
  float acc = fc1b[t];
  for (int k = 0; k < 128; ++k) acc += gs[k] * fc1w[k * 128 + t];
  a1[t] = fmaxf(acc, 0.f);
  __syncthreads();
  for (int c = t; c < 696; c += 128) {
    float s = fc2b[c];
    for (int k = 0; k < 128; ++k) s += a1[k] * fc2w[k * 696 + c];
    lg[c] = s;
  }
  __syncthreads();
  float m = -__builtin_inff();
  for (int c = t; c < 696; c += 128) m = fmaxf(m, lg[c]);
  for (int d = 32; d; d >>= 1) m = fmaxf(m, __shfl_xor(m, d, 64));
  if ((t & 63) == 0) wred[t >> 6] = m;
  __syncthreads();
  m = fmaxf(wred[0], wred[1]);
  __syncthreads();
  float se = 0.f;
  for (int c = t; c < 696; c += 128) se += expf(lg[c] - m);
  for (int d = 32; d; d >>= 1) se += __shfl_xor(se, d, 64);
  __shared__ float wred2[2];
  if ((t & 63) == 0) wred2[t >> 6] = se;
  __syncthreads();
  float lse = m + logf(wred2[0] + wred2[1]);
  for (int c = t; c < 696; c += 128) out[gr * 696 + c] = lg[c] - lse;
}

extern "C" void kernel_launch(void* const* d_in, const int* in_sizes, int n_in,
                              void* d_out, int out_size, void* d_ws, size_t ws_size,
                              hipStream_t stream) {
  const float* x    = (const float*)d_in[0];
  const int*   ei   = (const int*)d_in[1];
  const int*   batch= (const int*)d_in[2];
  const float* W1s  = (const float*)d_in[3];
  const float* b1s  = (const float*)d_in[4];
  const float* W2s  = (const float*)d_in[5];
  const float* b2s  = (const float*)d_in[6];
  const float* fc1w = (const float*)d_in[7];
  const float* fc1b = (const float*)d_in[8];
  const float* fc2w = (const float*)d_in[9];
  const float* fc2b = (const float*)d_in[10];
  float* out = (float*)d_out;

  char* ws = (char*)d_ws;
  size_t off = 0;
  auto alloc = [&](size_t bytes) -> void* {
    void* p = ws + off;
    off = (off + bytes + 255) & ~(size_t)255;
    return p;
  };
  float* z      = (float*)alloc((size_t)N_NODESC * 128 * 4);
  float* h      = (float*)alloc((size_t)N_NODESC * 128 * 4);
  int*   col    = (int*)alloc((size_t)N_EDGESC * 4);
  int*   rowptr = (int*)alloc((size_t)(N_NODESC + 1) * 4);
  int*   cursor = (int*)alloc((size_t)(N_NODESC + 1) * 4);
  int*   bsums  = (int*)alloc(128 * 4);
  float* g      = (float*)alloc(64 * 128 * 4);
  ushort* wthi  = (ushort*)alloc((size_t)8 * 16384 * 2);
  ushort* wtlo  = (ushort*)alloc((size_t)8 * 16384 * 2);

  const int n_scan = N_NODESC + 1;
  const int NB = (n_scan + 1023) / 1024;  // 98

  // CSR build (cursor doubles as counts)
  hipMemsetAsync(cursor, 0, (size_t)(N_NODESC + 1) * 4, stream);
  k_hist<<<dim3((N_EDGESC + 255) / 256), dim3(256), 0, stream>>>(ei, cursor, N_EDGESC);
  k_scan1<<<dim3(NB), dim3(1024), 0, stream>>>(cursor, rowptr, bsums, n_scan);
  k_scan2<<<dim3(1), dim3(64), 0, stream>>>(bsums, NB);
  k_scan3<<<dim3(NB), dim3(1024), 0, stream>>>(rowptr, bsums, cursor, n_scan);
  k_scatter<<<dim3((N_EDGESC + 255) / 256), dim3(256), 0, stream>>>(ei, cursor, col, N_EDGESC);

  // weight preprocessing
  k_wsplit<<<dim3(512), dim3(256), 0, stream>>>(W1s, W2s, wthi, wtlo);

  // 4 GIN layers
  for (int L = 0; L < 4; ++L) {
    const float* hin = (L == 0) ? x : h;
    k_aggr<<<dim3(N_NODESC / 4), dim3(256), 0, stream>>>(hin, rowptr, col, z, N_NODESC);
    k_gemm<<<dim3((N_NODESC + 63) / 64), dim3(256), 0, stream>>>(
        z, wthi + (size_t)L * 16384, wtlo + (size_t)L * 16384, b1s + L * 128, z, N_NODESC);
    k_gemm<<<dim3((N_NODESC + 63) / 64), dim3(256), 0, stream>>>(
        z, wthi + (size_t)(4 + L) * 16384, wtlo + (size_t)(4 + L) * 16384, b2s + L * 128, h, N_NODESC);
  }

  // pool + head
  hipMemsetAsync(g, 0, 64 * 128 * 4, stream);
  k_pool<<<dim3((N_NODESC + 255) / 256), dim3(256), 0, stream>>>(h, batch, g, N_NODESC);
  k_head<<<dim3(64), dim3(128), 0, stream>>>(g, fc1w, fc1b, fc2w, fc2b, out);
}